// Round 10
// baseline (133.930 us; speedup 1.0000x reference)
//
#include <hip/hip_runtime.h>
#include <stdint.h>

#define TAGS 10
#define START_TAG 8
#define STOP_TAG 9
#define NEGV (-10000.0f)
#define BIGNEG (-1.0e9f)

// DPP within 16-lane rows: ROW_ROR:r = 0x120+r, QUAD_PERM[1,0,3,2] = 0xB1.
#define DPP_I(x, ctrl) __builtin_amdgcn_update_dpp(0, (x), (ctrl), 0xF, 0xF, true)
// ds_swizzle BitMode XOR-r within 32-lane halves.
#define SWZ_I(x, r) __builtin_amdgcn_ds_swizzle((x), (((r) << 10) | 0x1F))

__device__ __forceinline__ float maxf3(float a, float b, float c) {
    return fmaxf(fmaxf(a, b), c);   // folds to v_max3_f32
}

// Inline-asm feat loads: structurally pinned. R3-R9's constant ~500cyc/step
// was the register allocator sinking plain-HIP prefetch loads to just before
// use (VGPR 28-48 in every round proves the pipeline arrays never lived).
// Asm outputs force the buffer registers live; the load->use distance is
// 2 phases (~1300 cyc) and cannot be shortened by regalloc.
#define GLOADI(dst, base, OFF) \
    asm volatile("global_load_dword %0, %1, off offset:" #OFF \
                 : "=v"(dst) : "v"(base))
#define GLOAD8(BUF, BASE) { \
    const float* gb_ = (BASE); \
    GLOADI(BUF[0], gb_, 0);   GLOADI(BUF[1], gb_, 40); \
    GLOADI(BUF[2], gb_, 80);  GLOADI(BUF[3], gb_, 120); \
    GLOADI(BUF[4], gb_, 160); GLOADI(BUF[5], gb_, 200); \
    GLOADI(BUF[6], gb_, 240); GLOADI(BUF[7], gb_, 280); }
// Counted wait: when consuming buffer X (loaded 2 phases ago), ops newer than
// X's 8 loads = 8+8 loads + <=2 block-stores => vmcnt(16) guarantees X retired
// (vmcnt retires in order; stores included in the count but never waited on).
#define WAITP { asm volatile("s_waitcnt vmcnt(16)" ::: "memory"); \
                __builtin_amdgcn_sched_barrier(0); }
#define PINFENCE __builtin_amdgcn_sched_barrier(0);

// ===========================================================================
// K1: split forward. Blocks [0,ABLK): half-A true Viterbi t in [0,H),
// 4 seqs/wave, 8-tag duplicated octets, DPP gathers. Blocks [ABLK,ABLK+B):
// half-B 8 basis recurrences for one seq, t in [H,len), ds_swizzle gathers.
// Backpointers: per 8-step block, each even lane accumulates 8 nibble-pair
// bytes into 2 VGPRs and stores ONE dwordx2 (32B/block/seq for A; 32B/block/
// basis for B) -- one store per phase keeps the vmcnt stream clean.
// ===========================================================================
__global__ __launch_bounds__(64, 1) void crf_split_fwd(
    const float* __restrict__ feats,
    const int*   __restrict__ lengths,
    const float* __restrict__ trans,
    uint8_t*     __restrict__ bpA,
    uint8_t*     __restrict__ bpB,
    float*       __restrict__ fvAo,
    float*       __restrict__ gws,
    int B, int T, int H, int ABLK)
{
    const int lane = threadIdx.x & 63;

    if ((int)blockIdx.x < ABLK) {
        // ---------------- half A ----------------
        const int grp  = lane >> 4;
        const int n    = lane & 15;
        const int m    = n & 7;
        const bool odd = (n & 1);
        const int b4   = blockIdx.x * 4;
        const int b    = min(b4 + grp, B - 1);

        const int len  = lengths[b];
        const int lenA = min(len, H);
        const int l0 = lengths[min(b4 + 0, B - 1)];
        const int l1 = lengths[min(b4 + 1, B - 1)];
        const int l2 = lengths[min(b4 + 2, B - 1)];
        const int l3 = lengths[min(b4 + 3, B - 1)];
        const int HA = min(max(max(l0, l1), max(l2, l3)), H);
        const int blocksA = (H + 6) >> 3;          // H multiple of 16

        int srcv[8];
        srcv[0] = n;
        srcv[1] = DPP_I(n, 0x121);  srcv[2] = DPP_I(n, 0x122);
        srcv[3] = DPP_I(n, 0x123);  srcv[4] = DPP_I(n, 0x124);
        srcv[5] = DPP_I(n, 0x125);  srcv[6] = DPP_I(n, 0x126);
        srcv[7] = DPP_I(n, 0x127);

        float trowR[8];
        int   rsrc[8];
#pragma unroll
        for (int r = 0; r < 8; ++r) {
            const int sq = srcv[r] & 7;
            trowR[r] = trans[m * TAGS + sq];
            rsrc[r]  = sq ^ 7;
        }

        const float* fb = feats + (size_t)b * T * TAGS + m;
        uint8_t* bpa_l = bpA + (size_t)b * blocksA * 32 + ((n >> 1) & 3) * 8;
        const bool stl = (n < 8) && !odd;

        float fv = trans[m * TAGS + START_TAG] + fb[0];   // t=0 closed form

#define KLEAF_A(r, ctrl) { \
        int rot_ = DPP_I(__float_as_int(fv), (ctrl)); \
        float lv_ = __int_as_float(rot_) + trowR[r]; \
        k##r = __int_as_float((__float_as_int(lv_) & ~7) | rsrc[r]); }

#define STEP_A(TI, FEAT, ACCST) { \
        const int t_ = (TI); \
        float k0, k1, k2, k3, k4, k5, k6, k7; \
        { float lv_ = fv + trowR[0]; \
          k0 = __int_as_float((__float_as_int(lv_) & ~7) | rsrc[0]); } \
        KLEAF_A(1, 0x121) KLEAF_A(2, 0x122) KLEAF_A(3, 0x123) \
        KLEAF_A(4, 0x124) KLEAF_A(5, 0x125) KLEAF_A(6, 0x126) \
        KLEAF_A(7, 0x127) \
        const float p1_ = maxf3(k0, k1, k2); \
        const float p2_ = maxf3(k3, k4, k5); \
        const float p3_ = maxf3(k6, k7, p1_); \
        const float mm_ = fmaxf(p2_, p3_); \
        const int idx_  = (__float_as_int(mm_) & 7) ^ 7; \
        const int pidx_ = DPP_I(idx_, 0xB1); \
        const uint32_t byte_ = (uint32_t)(odd ? (pidx_ | (idx_ << 4)) \
                                              : (idx_ | (pidx_ << 4))); \
        ACCST; \
        const float fvn_ = mm_ + (FEAT); \
        fv = (t_ < lenA) ? fvn_ : fv; }

#define PH_A(USE, LD, T0) { \
        GLOAD8(LD, fb + (size_t)min((T0) + 16, T - 8) * TAGS); \
        WAITP \
        uint32_t accl, acch; \
        STEP_A((T0) + 0, USE[0], accl = byte_) \
        STEP_A((T0) + 1, USE[1], accl |= byte_ << 8) \
        STEP_A((T0) + 2, USE[2], accl |= byte_ << 16) \
        STEP_A((T0) + 3, USE[3], accl |= byte_ << 24) \
        STEP_A((T0) + 4, USE[4], acch = byte_) \
        STEP_A((T0) + 5, USE[5], acch |= byte_ << 8) \
        STEP_A((T0) + 6, USE[6], acch |= byte_ << 16) \
        STEP_A((T0) + 7, USE[7], acch |= byte_ << 24) \
        if ((T0) < H) { \
            if (stl) *(uint2*)(bpa_l + (size_t)(((T0) - 1) >> 3) * 32) \
                         = make_uint2(accl, acch); } }

        PINFENCE
        float xb[8], yb[8], zb[8];
        GLOAD8(xb, fb + (size_t)1 * TAGS);
        GLOAD8(yb, fb + (size_t)min(9, T - 8) * TAGS);

        for (int t0 = 1; t0 < HA; t0 += 24) {
            PH_A(xb, zb, t0)
            PH_A(yb, xb, t0 + 8)
            PH_A(zb, yb, t0 + 16)
        }
#undef KLEAF_A
#undef STEP_A
#undef PH_A

        if (n < 8)
            fvAo[(size_t)b * 8 + m] = fv;
    } else {
        // ---------------- half B ----------------
        const int s = blockIdx.x - ABLK;
        if (s >= B) return;
        const int len = lengths[s];
        if (len <= H) return;

        const int p    = lane >> 3;       // basis octet
        const int n    = lane & 7;        // tag
        const bool odd = (n & 1);
        const int blocksB = (T - H + 7) >> 3;

        float trowR[8];
        int   rsrc[8];
#pragma unroll
        for (int r = 0; r < 8; ++r) {
            const int q = n ^ r;
            trowR[r] = trans[n * TAGS + q];
            rsrc[r]  = q ^ 7;
        }

        float g = (n == p) ? 0.0f : BIGNEG;
        const float* fb = feats + (size_t)s * T * TAGS + n;
        uint8_t* bpb_l = bpB + (size_t)s * blocksB * 256 + p * 32 + (n >> 1) * 8;

#define KLEAF_B(r) { \
        int rot_ = SWZ_I(__float_as_int(g), r); \
        float lv_ = __int_as_float(rot_) + trowR[r]; \
        k##r = __int_as_float((__float_as_int(lv_) & ~7) | rsrc[r]); }

#define STEP_B(TI, FEAT, ACCST) { \
        const int t_ = (TI); \
        float k0, k1, k2, k3, k4, k5, k6, k7; \
        { float lv_ = g + trowR[0]; \
          k0 = __int_as_float((__float_as_int(lv_) & ~7) | rsrc[0]); } \
        KLEAF_B(1) KLEAF_B(2) KLEAF_B(3) KLEAF_B(4) \
        KLEAF_B(5) KLEAF_B(6) KLEAF_B(7) \
        const float p1_ = maxf3(k0, k1, k2); \
        const float p2_ = maxf3(k3, k4, k5); \
        const float p3_ = maxf3(k6, k7, p1_); \
        const float mm_ = fmaxf(p2_, p3_); \
        const int idx_  = (__float_as_int(mm_) & 7) ^ 7; \
        const int pidx_ = SWZ_I(idx_, 1); \
        const uint32_t byte_ = (uint32_t)(odd ? (pidx_ | (idx_ << 4)) \
                                              : (idx_ | (pidx_ << 4))); \
        ACCST; \
        g = (t_ < len) ? (mm_ + (FEAT)) : g; }

#define PH_B(USE, LD, T0) { \
        GLOAD8(LD, fb + (size_t)min((T0) + 16, T - 8) * TAGS); \
        WAITP \
        uint32_t accl, acch; \
        STEP_B((T0) + 0, USE[0], accl = byte_) \
        STEP_B((T0) + 1, USE[1], accl |= byte_ << 8) \
        STEP_B((T0) + 2, USE[2], accl |= byte_ << 16) \
        STEP_B((T0) + 3, USE[3], accl |= byte_ << 24) \
        STEP_B((T0) + 4, USE[4], acch = byte_) \
        STEP_B((T0) + 5, USE[5], acch |= byte_ << 8) \
        STEP_B((T0) + 6, USE[6], acch |= byte_ << 16) \
        STEP_B((T0) + 7, USE[7], acch |= byte_ << 24) \
        if ((T0) < T) { \
            if (!odd) *(uint2*)(bpb_l + (size_t)(((T0) - H) >> 3) * 256) \
                          = make_uint2(accl, acch); } }

        PINFENCE
        float xb[8], yb[8], zb[8];
        GLOAD8(xb, fb + (size_t)H * TAGS);
        GLOAD8(yb, fb + (size_t)min(H + 8, T - 8) * TAGS);

        for (int t0 = H; t0 < len; t0 += 24) {
            PH_B(xb, zb, t0)
            PH_B(yb, xb, t0 + 8)
            PH_B(zb, yb, t0 + 16)
        }
#undef KLEAF_B
#undef STEP_B
#undef PH_B

        gws[(size_t)s * 64 + lane] = g;   // lane = p*8 + n
    }
}

// ===========================================================================
// K2: seam + terminal + two independent blocked backtrace walks per seq.
// bp block layout (32B per 8 steps): byte for (step j, tag pair P) lives at
// dword 2P + (j>>2), byte (j&3); nibble 4*(tag&1). Chase = 3 cndmask + shift.
// ===========================================================================
__global__ __launch_bounds__(64, 1) void crf_split_bt(
    const int*     __restrict__ lengths,
    const float*   __restrict__ trans,
    const uint8_t* __restrict__ bpA,
    const uint8_t* __restrict__ bpB,
    const float*   __restrict__ fvA,
    const float*   __restrict__ gws,
    float*         __restrict__ out_scores,
    float*         __restrict__ out_path,
    int B, int T, int H)
{
    const int rb = (B + 63) >> 6;
    const bool roleB = ((int)blockIdx.x < rb);
    const int s = (roleB ? (int)blockIdx.x : (int)blockIdx.x - rb) * 64 + threadIdx.x;
    if (s >= B) return;
    const int len = lengths[s];
    const int blocksA = (H + 6) >> 3;
    const int blocksB = (T - H + 7) >> 3;

    float fa[8];
    {
        const float4* f4 = (const float4*)(fvA + (size_t)s * 8);
        float4 a = f4[0], c = f4[1];
        fa[0]=a.x; fa[1]=a.y; fa[2]=a.z; fa[3]=a.w;
        fa[4]=c.x; fa[5]=c.y; fa[6]=c.z; fa[7]=c.w;
    }
    const float* gr = gws + (size_t)s * 64;
    float fv[8];
    if (len > H) {
#pragma unroll
        for (int nn = 0; nn < 8; ++nn) fv[nn] = fa[0] + gr[nn];
#pragma unroll
        for (int pp = 1; pp < 8; ++pp)
#pragma unroll
            for (int nn = 0; nn < 8; ++nn)
                fv[nn] = fmaxf(fv[nn], fa[pp] + gr[pp * 8 + nn]);
    } else {
#pragma unroll
        for (int nn = 0; nn < 8; ++nn) fv[nn] = fa[nn];
    }

    float best = fv[0] + trans[STOP_TAG * TAGS + 0];
    int ltag = 0;
#pragma unroll
    for (int nn = 1; nn < 8; ++nn) {
        const float tv = fv[nn] + trans[STOP_TAG * TAGS + nn];
        if (tv > best) { best = tv; ltag = nn; }
    }
    int pstar = 0;
    if (len > H) {
        float bb = fa[0] + gr[ltag];
#pragma unroll
        for (int pp = 1; pp < 8; ++pp) {
            const float v = fa[pp] + gr[pp * 8 + ltag];
            if (v > bb) { bb = v; pstar = pp; }
        }
    }

    float* orow = out_path + (size_t)s * T;

#define CHASE(J) { \
        const uint32_t sA_ = (tag & 2) ? d[2 + ((J) >> 2)] : d[((J) >> 2)]; \
        const uint32_t sB_ = (tag & 2) ? d[6 + ((J) >> 2)] : d[4 + ((J) >> 2)]; \
        const uint32_t sel_ = (tag & 4) ? sB_ : sA_; \
        tag = (int)((sel_ >> (8 * ((J) & 3) + 4 * (tag & 1))) & 7); }

    if (roleB) {
        out_scores[s] = best;
        int tag = ltag;
        const uint8_t* bb8 = bpB + (size_t)s * blocksB * 256 + pstar * 32;
        for (int k = blocksB - 1; k >= 0; --k) {
            const uint4 qa = *(const uint4*)(bb8 + (size_t)k * 256);
            const uint4 qb = *(const uint4*)(bb8 + (size_t)k * 256 + 16);
            const uint32_t d[8] = {qa.x, qa.y, qa.z, qa.w, qb.x, qb.y, qb.z, qb.w};
            float buf[8];
#pragma unroll
            for (int u = 7; u >= 0; --u) {
                const int t = H + 8 * k + u;
                if (t < T) {
                    const bool act = t < len;
                    buf[u] = act ? (float)tag : 0.0f;
                    if (act) CHASE(u)
                }
            }
            const int t0 = H + 8 * k;
#pragma unroll
            for (int j = 0; j < 8; j += 4) {
                const int t = t0 + j;
                if (t + 3 < T) {
                    *(float4*)(orow + t) = make_float4(buf[j], buf[j+1], buf[j+2], buf[j+3]);
                } else {
#pragma unroll
                    for (int q = 0; q < 4; ++q)
                        if (t + q < T) orow[t + q] = buf[j + q];
                }
            }
        }
    } else {
        const int lenA = min(len, H);
        int tag = (len > H) ? pstar : ltag;
        const uint8_t* ab8 = bpA + (size_t)s * blocksA * 32;
        for (int k = blocksA - 1; k >= 0; --k) {
            const uint4 qa = *(const uint4*)(ab8 + (size_t)k * 32);
            const uint4 qb = *(const uint4*)(ab8 + (size_t)k * 32 + 16);
            const uint32_t d[8] = {qa.x, qa.y, qa.z, qa.w, qb.x, qb.y, qb.z, qb.w};
#pragma unroll
            for (int u = 7; u >= 0; --u) {
                const int t = 8 * k + 1 + u;
                if (t < H) {
                    const bool act = t < lenA;
                    orow[t] = act ? (float)tag : 0.0f;
                    if (act) CHASE(u)
                }
            }
        }
        orow[0] = (float)tag;   // state at t=0 (len >= 1 always)
    }
#undef CHASE
}

// ===========================================================================
// Fallback (ws too small): R8 fused kernel verbatim.
// ===========================================================================
__global__ __launch_bounds__(64, 1) void crf_fused_small(
    const float* __restrict__ feats,
    const int*   __restrict__ lengths,
    const float* __restrict__ trans,
    float*       __restrict__ out_scores,
    float*       __restrict__ out_path,
    uint8_t*     __restrict__ bp4,
    int B, int T)
{
    const int lane = threadIdx.x & 63;
    const int grp  = lane >> 4;
    const int n    = lane & 15;
    const int m    = n & 7;
    const bool odd = (n & 1);
    const int b4   = blockIdx.x * 4;
    const int b    = min(b4 + grp, B - 1);

    const int len = lengths[b];
    const int l0 = lengths[min(b4 + 0, B - 1)];
    const int l1 = lengths[min(b4 + 1, B - 1)];
    const int l2 = lengths[min(b4 + 2, B - 1)];
    const int l3 = lengths[min(b4 + 3, B - 1)];
    const int maxlen = max(max(l0, l1), max(l2, l3));

    int srcv[8];
    srcv[0] = n;
    srcv[1] = DPP_I(n, 0x121);  srcv[2] = DPP_I(n, 0x122);
    srcv[3] = DPP_I(n, 0x123);  srcv[4] = DPP_I(n, 0x124);
    srcv[5] = DPP_I(n, 0x125);  srcv[6] = DPP_I(n, 0x126);
    srcv[7] = DPP_I(n, 0x127);

    float trowR[8];
    int   rsrc[8];
#pragma unroll
    for (int r = 0; r < 8; ++r) {
        const int sq = srcv[r] & 7;
        trowR[r] = trans[m * TAGS + sq];
        rsrc[r]  = sq ^ 7;
    }

    const float* fb = feats + (size_t)b * T * TAGS + m;
    uint8_t* bpb = bp4 + (size_t)b * T * 4 + (n >> 1);
    const bool store_lane = (n < 8) && !odd;

    float fv = trans[m * TAGS + START_TAG] + fb[0];

#define KLEAF_S(r, ctrl) { \
        int rot_ = DPP_I(__float_as_int(fv), (ctrl)); \
        float lv_ = __int_as_float(rot_) + trowR[r]; \
        k##r = __int_as_float((__float_as_int(lv_) & ~7) | rsrc[r]); }

#define STEP_S(TI, FEAT) { \
        const int t_ = (TI); \
        float k0, k1, k2, k3, k4, k5, k6, k7; \
        { float lv_ = fv + trowR[0]; \
          k0 = __int_as_float((__float_as_int(lv_) & ~7) | rsrc[0]); } \
        KLEAF_S(1, 0x121) KLEAF_S(2, 0x122) KLEAF_S(3, 0x123) \
        KLEAF_S(4, 0x124) KLEAF_S(5, 0x125) KLEAF_S(6, 0x126) \
        KLEAF_S(7, 0x127) \
        const float p1_ = maxf3(k0, k1, k2); \
        const float p2_ = maxf3(k3, k4, k5); \
        const float p3_ = maxf3(k6, k7, p1_); \
        const float mm_ = fmaxf(p2_, p3_); \
        const int   idx_  = (__float_as_int(mm_) & 7) ^ 7; \
        const int   pidx_ = DPP_I(idx_, 0xB1); \
        const int   lo_   = odd ? pidx_ : idx_; \
        const int   hi_   = odd ? idx_ : pidx_; \
        const float fvn_  = mm_ + (FEAT); \
        fv = (t_ < len) ? fvn_ : fv; \
        if (t_ < T) { \
            if (store_lane) \
                bpb[(size_t)t_ * 4] = (uint8_t)(lo_ | (hi_ << 4)); \
        } }

    float fc[8], fn[8];
#pragma unroll
    for (int i = 0; i < 8; ++i)
        fc[i] = fb[(size_t)min(1 + i, T - 1) * TAGS];

    for (int t0 = 1; t0 < maxlen; t0 += 8) {
#pragma unroll
        for (int i = 0; i < 8; ++i)
            fn[i] = fb[(size_t)min(t0 + 8 + i, T - 1) * TAGS];

        STEP_S(t0 + 0, fc[0]) STEP_S(t0 + 1, fc[1])
        STEP_S(t0 + 2, fc[2]) STEP_S(t0 + 3, fc[3])
        STEP_S(t0 + 4, fc[4]) STEP_S(t0 + 5, fc[5])
        STEP_S(t0 + 6, fc[6]) STEP_S(t0 + 7, fc[7])

#pragma unroll
        for (int i = 0; i < 8; ++i) fc[i] = fn[i];
    }
#undef KLEAF_S
#undef STEP_S

    const float term = fv + trans[STOP_TAG * TAGS + m];
    float kk = __int_as_float((__float_as_int(term) & ~7) | (m ^ 7));
    kk = fmaxf(kk, __int_as_float(DPP_I(__float_as_int(kk), 0x124)));
    kk = fmaxf(kk, __int_as_float(DPP_I(__float_as_int(kk), 0x122)));
    kk = fmaxf(kk, __int_as_float(DPP_I(__float_as_int(kk), 0x121)));
    int tag = (__float_as_int(kk) & 7) ^ 7;

    if (n == 0)
        out_scores[b] = kk;

    __builtin_amdgcn_s_waitcnt(0);
    __builtin_amdgcn_sched_barrier(0);

    if (n == 0) {
        const uint32_t* rw = (const uint32_t*)(bp4 + (size_t)b * T * 4);
        float* orow = out_path + (size_t)b * T;
        const int NB = (T + 15) / 16;
        uint32_t wA[16], wB[16];

        auto loadblk = [&](int bi, uint32_t* w) {
            if (bi < 0) return;
#pragma unroll
            for (int j = 0; j < 4; ++j) {
                const int tb = min(bi * 16 + 4 * j, T - 4);
                *(uint4*)&w[4 * j] = *(const uint4*)&rw[tb];
            }
        };
        auto compblk = [&](int bi, uint32_t* w) {
            float buf[16];
#pragma unroll
            for (int u = 15; u >= 0; --u) {
                const int t = bi * 16 + u;
                if (t < T) {
                    const bool act = t < len;
                    buf[u] = act ? (float)tag : 0.0f;
                    if (act) tag = (int)((w[u] >> (4 * tag)) & 15);
                }
            }
#pragma unroll
            for (int j = 0; j < 16; j += 4) {
                const int t = bi * 16 + j;
                if (t + 3 < T)
                    *(float4*)(orow + t) = make_float4(buf[j], buf[j+1], buf[j+2], buf[j+3]);
            }
        };

        int bi = NB - 1;
        loadblk(bi, wA);
        loadblk(bi - 1, wB);
        for (; bi >= 0; bi -= 2) {
            compblk(bi, wA);
            loadblk(bi - 2, wA);
            if (bi - 1 >= 0) compblk(bi - 1, wB);
            loadblk(bi - 3, wB);
        }
    }
}

extern "C" void kernel_launch(void* const* d_in, const int* in_sizes, int n_in,
                              void* d_out, int out_size, void* d_ws, size_t ws_size,
                              hipStream_t stream)
{
    const float* feats   = (const float*)d_in[0];
    const int*   lengths = (const int*)d_in[1];
    const float* trans   = (const float*)d_in[2];
    const int B = in_sizes[1];
    const int T = in_sizes[0] / (B * TAGS);

    float* out_scores = (float*)d_out;       // [B]
    float* out_path   = (float*)d_out + B;   // [B, T] tags as floats

    // pick smallest H (multiple of 16) whose workspace fits
    int H = ((T / 2) + 15) & ~15;
    size_t need = 0;
    bool ok = false;
    for (; H + 16 < T; H += 16) {
        const size_t blocksA = (size_t)((H + 6) >> 3);
        const size_t blocksB = (size_t)((T - H + 7) >> 3);
        need = (size_t)B * (blocksA * 32 + blocksB * 256 + 32 + 256);
        if (need <= ws_size) { ok = true; break; }
    }

    if (ok && T > 64 && (T & 3) == 0) {
        const size_t blocksA = (size_t)((H + 6) >> 3);
        const size_t blocksB = (size_t)((T - H + 7) >> 3);
        uint8_t* bpA  = (uint8_t*)d_ws;
        uint8_t* bpB  = bpA + (size_t)B * blocksA * 32;
        float*   fvAo = (float*)(bpB + (size_t)B * blocksB * 256);
        float*   gws  = fvAo + (size_t)B * 8;
        const int ABLK = (B + 3) / 4;

        crf_split_fwd<<<ABLK + B, 64, 0, stream>>>(
            feats, lengths, trans, bpA, bpB, fvAo, gws, B, T, H, ABLK);

        const int rb = (B + 63) >> 6;
        crf_split_bt<<<2 * rb, 64, 0, stream>>>(
            lengths, trans, bpA, bpB, fvAo, gws, out_scores, out_path, B, T, H);
    } else {
        uint8_t* bp4 = (uint8_t*)d_ws;       // [B][T] 4B words
        crf_fused_small<<<(B + 3) / 4, 64, 0, stream>>>(
            feats, lengths, trans, out_scores, out_path, bp4, B, T);
    }
}